// Round 4
// baseline (215.324 us; speedup 1.0000x reference)
//
#include <hip/hip_runtime.h>
#include <math.h>

#define IMG_W 2048
#define IMG_H 2048
#define BATCH 8
#define MAX_PEAKS ((BATCH * IMG_H * IMG_W) / 8)   // 4194304
#define NWORDS (BATCH * IMG_H * IMG_W / 32)       // 1048576
#define ROWSW 32                                  // rows per wave
#define NFILL 2048                                // tail-fill blocks

// ---------------------------------------------------------------------------
// K1: software-pipelined register-window NMS mask.
// Wave owns a 256-col strip x 32 rows; lane = 4 cols (float4 loads).
// 12-row register window W[] + 8-row prefetch batch T[]: each stage issues
// ALL next-batch loads before computing the current 8 output rows, giving a
// full batch (~700 cyc) of load->use distance and 16 loads in flight/wave.
// Horizontal +-2 halo via shfl_up/down; edge halo via one unconditional
// 64-lane load (lanes 0..31 -> left-edge float4, 32..63 -> right-edge).
// OOB rows/cols: address clamped, value forced to -inf via select.
// mask bit = (s > 0) && (s >= 5x5 window max)
// ---------------------------------------------------------------------------
__device__ __forceinline__ void load_row(const float* __restrict__ colp,
                                         const float* __restrict__ ecolp,
                                         int gr, bool leftHalf, bool evalid,
                                         float4& nv, float2& ne) {
    const float NEG = -INFINITY;
    int rc = gr < 0 ? 0 : (gr > IMG_H - 1 ? IMG_H - 1 : gr);
    size_t off = (size_t)rc * IMG_W;
    float4 v = *(const float4*)(colp + off);    // unconditional
    float4 ev = *(const float4*)(ecolp + off);  // unconditional, 2 segs/wave
    bool rv = ((unsigned)gr < IMG_H);
    bool ok = rv && evalid;
    float ex = leftHalf ? ev.z : ev.x;
    float ey = leftHalf ? ev.w : ev.y;
    nv.x = rv ? v.x : NEG;
    nv.y = rv ? v.y : NEG;
    nv.z = rv ? v.z : NEG;
    nv.w = rv ? v.w : NEG;
    ne.x = ok ? ex : NEG;
    ne.y = ok ? ey : NEG;
}

__global__ __launch_bounds__(256, 2) void nms_mask(const float* __restrict__ scores,
                                                   unsigned* __restrict__ words,
                                                   unsigned* __restrict__ bsum2) {
    const int t = threadIdx.x;
    const int lane = t & 63;
    const int wv = t >> 6;            // wave in block: 0..3
    const int b = blockIdx.x;         // 0..1023
    const int img = b >> 7;           // 8 images x 128 blocks
    const int rem = b & 127;
    const int strip = rem >> 4;       // 8 column strips of 256
    const int chunk = rem & 15;       // 16 row chunks of 128
    const int r0 = chunk * 128 + wv * ROWSW;
    const int c0 = strip * 256;
    const int cl = c0 + lane * 4;
    const size_t imgBase = (size_t)img * (IMG_H * IMG_W);

    const float* colp = scores + imgBase + cl;
    const bool leftHalf = (lane < 32);
    const bool isL = (lane == 0), isR = (lane == 63);
    int ecol = leftHalf ? (c0 - 4) : (c0 + 256);
    const bool evalid = ((unsigned)ecol < IMG_W);
    int ecolC = evalid ? ecol : c0;                 // clamped valid address
    const float* ecolp = scores + imgBase + ecolC;

    float4 W[12];
    float2 WE[12];

    // prologue: rows r0-2 .. r0+9 -> W[0..11]
#pragma unroll
    for (int m = 0; m < 12; ++m)
        load_row(colp, ecolp, r0 - 2 + m, leftHalf, evalid, W[m], WE[m]);

    unsigned cnt = 0;
    const int shamt = (lane & 7) * 4;
    size_t wIdx = (size_t)(img * IMG_H + r0) * (IMG_W / 32) + strip * 8 + (lane >> 3);
    const int cb0 = (img * IMG_H + r0) >> 4;   // compact-block (16-row) index
    const bool writer = ((lane & 7) == 0);

#pragma unroll
    for (int k = 0; k < 4; ++k) {
        // issue ALL next-batch loads first (rows r0+10+8k .. r0+17+8k)
        float4 T[8];
        float2 TE[8];
        if (k < 3) {
#pragma unroll
            for (int j = 0; j < 8; ++j)
                load_row(colp, ecolp, r0 + 10 + 8 * k + j, leftHalf, evalid,
                         T[j], TE[j]);
        }

        // compute 8 output rows r0+8k .. r0+8k+7 from resident W/WE only
#pragma unroll
        for (int i = 0; i < 8; ++i) {
            const float4 w0 = W[i];
            const float4 w1 = W[i + 1];
            const float4 mid = W[i + 2];
            const float4 w3 = W[i + 3];
            const float4 w4 = W[i + 4];
            float vmx = fmaxf(fmaxf(fmaxf(w0.x, w1.x), fmaxf(mid.x, w3.x)), w4.x);
            float vmy = fmaxf(fmaxf(fmaxf(w0.y, w1.y), fmaxf(mid.y, w3.y)), w4.y);
            float vmz = fmaxf(fmaxf(fmaxf(w0.z, w1.z), fmaxf(mid.z, w3.z)), w4.z);
            float vmw = fmaxf(fmaxf(fmaxf(w0.w, w1.w), fmaxf(mid.w, w3.w)), w4.w);
            const float2 e0 = WE[i];
            const float2 e1 = WE[i + 1];
            const float2 e2 = WE[i + 2];
            const float2 e3 = WE[i + 3];
            const float2 e4 = WE[i + 4];
            float vex = fmaxf(fmaxf(fmaxf(e0.x, e1.x), fmaxf(e2.x, e3.x)), e4.x);
            float vey = fmaxf(fmaxf(fmaxf(e0.y, e1.y), fmaxf(e2.y, e3.y)), e4.y);

            // horizontal halo: left neighbor cols (z,w), right neighbor (x,y)
            float A = __shfl_up(vmz, 1);
            float B = __shfl_up(vmw, 1);
            float C = __shfl_down(vmx, 1);
            float D = __shfl_down(vmy, 1);
            if (isL) { A = vex; B = vey; }
            if (isR) { C = vex; D = vey; }

            float t12 = fmaxf(vmy, vmz);
            float m02 = fmaxf(vmx, t12);        // max cols 0..2
            float m03 = fmaxf(m02, vmw);        // max cols 0..3
            float m13 = fmaxf(t12, vmw);        // max cols 1..3
            float h0 = fmaxf(fmaxf(A, B), m02);
            float h1 = fmaxf(B, m03);
            float h2 = fmaxf(m03, C);
            float h3 = fmaxf(m13, fmaxf(C, D));

            unsigned nib = 0;
            nib |= (mid.x > 0.0f && mid.x >= h0) ? 1u : 0u;
            nib |= (mid.y > 0.0f && mid.y >= h1) ? 2u : 0u;
            nib |= (mid.z > 0.0f && mid.z >= h2) ? 4u : 0u;
            nib |= (mid.w > 0.0f && mid.w >= h3) ? 8u : 0u;

            unsigned wd = nib << shamt;
            wd |= __shfl_xor(wd, 1);
            wd |= __shfl_xor(wd, 2);
            wd |= __shfl_xor(wd, 4);
            if (writer) {
                words[wIdx] = wd;
                cnt += __popc(wd);
            }
            wIdx += IMG_W / 32;
        }

        if (k & 1) {   // flush per 16 output rows -> per-(chunk,strip) slot
            unsigned s = cnt;
            s += __shfl_xor(s, 1);
            s += __shfl_xor(s, 2);
            s += __shfl_xor(s, 4);
            s += __shfl_xor(s, 8);
            s += __shfl_xor(s, 16);
            s += __shfl_xor(s, 32);
            if (lane == 0) bsum2[(cb0 + (k >> 1)) * 8 + strip] = s;
            cnt = 0;
        }

        if (k < 3) {   // shift window (pure renaming after full unroll)
#pragma unroll
            for (int m = 0; m < 4; ++m) { W[m] = W[m + 8]; WE[m] = WE[m + 8]; }
#pragma unroll
            for (int m = 0; m < 8; ++m) { W[m + 4] = T[m]; WE[m + 4] = TE[m]; }
        }
    }
}

// ---------------------------------------------------------------------------
// K2: scan. Reduce 8 strip-sums per 16-row chunk (8192 slots -> 1024 cbs),
// exclusive scan, base[1024] = total. One 256-thread block.
// ---------------------------------------------------------------------------
__global__ __launch_bounds__(256) void nms_scan(const unsigned* __restrict__ bsum2,
                                                unsigned* __restrict__ base) {
    __shared__ unsigned wtot[4];
    const int t = threadIdx.x;
    const int lane = t & 63, wid = t >> 6;
    const uint4* p = (const uint4*)(bsum2 + t * 32);   // 4 cbs x 8 slots
    unsigned c[4];
#pragma unroll
    for (int i = 0; i < 4; ++i) {
        uint4 a = p[2 * i], bq = p[2 * i + 1];
        c[i] = a.x + a.y + a.z + a.w + bq.x + bq.y + bq.z + bq.w;
    }
    unsigned s0 = c[0], s1 = s0 + c[1], s2 = s1 + c[2], ts = s2 + c[3];
    unsigned sc = ts;
#pragma unroll
    for (int d = 1; d < 64; d <<= 1) {
        unsigned o = __shfl_up(sc, d);
        if (lane >= d) sc += o;
    }
    if (lane == 63) wtot[wid] = sc;
    __syncthreads();
    unsigned wpre = 0;
#pragma unroll
    for (int k = 0; k < 4; ++k) wpre += (k < wid) ? wtot[k] : 0u;
    unsigned excl = wpre + sc - ts;
    ((uint4*)base)[t] = make_uint4(excl, excl + s0, excl + s1, excl + s2);
    if (t == 255) base[1024] = wpre + sc;
}

// ---------------------------------------------------------------------------
// K3: ordered compaction (blocks 0..1023) + -1 tail fill (blocks 1024..)
// ---------------------------------------------------------------------------
__global__ __launch_bounds__(256) void nms_compact(const unsigned* __restrict__ words,
                                                   const unsigned* __restrict__ base,
                                                   int* __restrict__ out) {
    const int t = threadIdx.x;
    const int b = blockIdx.x;
    if (b < 1024) {
        __shared__ unsigned wq[4];
        const int lane = t & 63, wid = t >> 6;
        uint4 q = ((const uint4*)(words + b * 1024))[t];
        unsigned wv[4] = {q.x, q.y, q.z, q.w};
        unsigned tsum = __popc(wv[0]) + __popc(wv[1]) + __popc(wv[2]) + __popc(wv[3]);
        unsigned sc = tsum;
#pragma unroll
        for (int d = 1; d < 64; d <<= 1) {
            unsigned o = __shfl_up(sc, d);
            if (lane >= d) sc += o;
        }
        if (lane == 63) wq[wid] = sc;
        __syncthreads();
        unsigned wpre = 0;
#pragma unroll
        for (int k = 0; k < 4; ++k) wpre += (k < wid) ? wq[k] : 0u;
        unsigned off = base[b] + wpre + sc - tsum;

        const unsigned gword0 = (unsigned)b * 1024u + (unsigned)t * 4u;
#pragma unroll
        for (int wi = 0; wi < 4; ++wi) {
            unsigned m = wv[wi];
            unsigned pbase = (gword0 + wi) << 5;
            while (m) {
                int bit = __builtin_ctz(m);
                m &= m - 1;
                unsigned ppix = pbase + (unsigned)bit;
                int hh = (int)((ppix >> 11) & 2047u);
                int ww = (int)(ppix & 2047u);
                if (off < (unsigned)MAX_PEAKS) {
                    out[off] = hh;
                    out[MAX_PEAKS + off] = ww;
                }
                ++off;
            }
        }
    } else {
        unsigned total = base[1024];
        if (total > (unsigned)MAX_PEAKS) total = MAX_PEAKS;
        unsigned tail = (unsigned)MAX_PEAKS - total;
        unsigned fb = (unsigned)(b - 1024);
        unsigned per = (tail + NFILL - 1) / NFILL;
        unsigned s = total + fb * per;
        unsigned e = s + per;
        if (e > (unsigned)MAX_PEAKS) e = MAX_PEAKS;
        for (unsigned k = s + t; k < e; k += 256) {
            out[k] = -1;
            out[MAX_PEAKS + k] = -1;
        }
    }
}

extern "C" void kernel_launch(void* const* d_in, const int* in_sizes, int n_in,
                              void* d_out, int out_size, void* d_ws, size_t ws_size,
                              hipStream_t stream) {
    const float* scores = (const float*)d_in[0];
    int* out = (int*)d_out;
    unsigned* words = (unsigned*)d_ws;            // 1,048,576 words (4 MB)
    unsigned* bsum2 = words + NWORDS;             // 8192 per-(chunk,strip) sums
    unsigned* base = bsum2 + 8192;                // 1025 (incl. total)

    nms_mask<<<1024, 256, 0, stream>>>(scores, words, bsum2);
    nms_scan<<<1, 256, 0, stream>>>(bsum2, base);
    nms_compact<<<1024 + NFILL, 256, 0, stream>>>(words, base, out);
}

// Round 5
// 215.073 us; speedup vs baseline: 1.0012x; 1.0012x over previous
//
#include <hip/hip_runtime.h>
#include <math.h>

#define IMG_W 2048
#define IMG_H 2048
#define BATCH 8
#define MAX_PEAKS ((BATCH * IMG_H * IMG_W) / 8)   // 4194304
#define NWORDS (BATCH * IMG_H * IMG_W / 32)       // 1048576
#define ROWSW 32                                  // rows per wave
#define NFILL 2048                                // tail-fill blocks

// ---------------------------------------------------------------------------
// K1: register-ring NMS mask with RAW loads (no VALU touches a load result
// until its fmax consumption ~7 iterations later).
// - Wave owns 256 cols x 32 rows; lane = 4 cols (float4).
// - Edge halo: per-lane pre-offset float2 load (left lanes read cols c0-2,
//   c0-1; right lanes cols c0+256,c0+257) -> lands directly in ring, no
//   selects. Validity applied post-reduction on vex/vey only.
// - Row OOB: prologue fixed up once (r0==0); only iters 23,24 (rows r0+32/33,
//   OOB only for bottom wave) carry a select.
// - Ring depth 12, full unroll: load row r0+9+i at iter i, consumed at iter
//   i+7 => ~14 loads in flight, no intervening dependent VALU.
// mask bit = (s > 0) && (s >= 5x5 window max)
// ---------------------------------------------------------------------------
__global__ __launch_bounds__(256, 4) void nms_mask(const float* __restrict__ scores,
                                                   unsigned* __restrict__ words,
                                                   unsigned* __restrict__ bsum2) {
    const int t = threadIdx.x;
    const int lane = t & 63;
    const int wv = t >> 6;            // wave in block: 0..3
    const int b = blockIdx.x;         // 0..1023
    const int img = b >> 7;           // 8 images x 128 blocks
    const int rem = b & 127;
    const int strip = rem >> 4;       // 8 column strips of 256
    const int chunk = rem & 15;       // 16 row chunks of 128
    const int r0 = chunk * 128 + wv * ROWSW;
    const int c0 = strip * 256;
    const int cl = c0 + lane * 4;
    const size_t imgBase = (size_t)img * (IMG_H * IMG_W);

    const float* colp = scores + imgBase + cl;
    const bool leftHalf = (lane < 32);
    const bool isL = (lane == 0), isR = (lane == 63);
    const int ecol = leftHalf ? (c0 - 4) : (c0 + 256);
    const bool evalid = ((unsigned)ecol < IMG_W);
    const int ecolC = evalid ? ecol : c0;           // clamped valid address
    // per-lane constant sub-offset: left lanes need (ecol+2, ecol+3),
    // right lanes need (ecol, ecol+1) -> direct float2 load, zero selects
    const float* ecolp2 = scores + imgBase + ecolC + (leftHalf ? 2 : 0);

    const float NEG = -INFINITY;
    float4 R[12];
    float2 E[12];

    // prologue: rows r0-2 .. r0+8 -> slots 0..10 (raw, low-clamped addr)
#pragma unroll
    for (int m = 0; m < 11; ++m) {
        int gr = r0 - 2 + m;
        int rc = gr < 0 ? 0 : gr;     // rows r0+1..r0+8 always < IMG_H
        size_t off = (size_t)rc * IMG_W;
        R[m] = *(const float4*)(colp + off);
        E[m] = *(const float2*)(ecolp2 + off);
    }
    if (r0 == 0) {                    // wave-uniform fixup, runs once
#pragma unroll
        for (int m = 0; m < 2; ++m) {
            R[m] = make_float4(NEG, NEG, NEG, NEG);
            E[m] = make_float2(NEG, NEG);
        }
    }
    const bool bot = (r0 + 32) >= IMG_H;   // bottom wave: rows r0+32/33 OOB

    unsigned cnt = 0;
    const int shamt = (lane & 7) * 4;
    size_t wIdx = (size_t)(img * IMG_H + r0) * (IMG_W / 32) + strip * 8 + (lane >> 3);
    const int cb0 = (img * IMG_H + r0) >> 4;   // compact-block (16-row) index
    const bool writer = ((lane & 7) == 0);

#pragma unroll
    for (int i = 0; i < 32; ++i) {
        // ---- issue next load: row r0+9+i -> slot (11+i)%12 ----
        if (i < 25) {
            int gr = r0 + 9 + i;
            int rc = gr > IMG_H - 1 ? IMG_H - 1 : gr;
            size_t off = (size_t)rc * IMG_W;
            float4 v = *(const float4*)(colp + off);
            float2 e = *(const float2*)(ecolp2 + off);
            if (i >= 23) {            // rows r0+32, r0+33
                if (bot) {
                    v = make_float4(NEG, NEG, NEG, NEG);
                    e = make_float2(NEG, NEG);
                }
            }
            R[(11 + i) % 12] = v;
            E[(11 + i) % 12] = e;
        }

        // ---- compute output row r0+i from slots i%12 .. (i+4)%12 ----
        const float4 w0 = R[(i) % 12];
        const float4 w1 = R[(i + 1) % 12];
        const float4 mid = R[(i + 2) % 12];
        const float4 w3 = R[(i + 3) % 12];
        const float4 w4 = R[(i + 4) % 12];
        float vmx = fmaxf(fmaxf(fmaxf(w0.x, w1.x), fmaxf(mid.x, w3.x)), w4.x);
        float vmy = fmaxf(fmaxf(fmaxf(w0.y, w1.y), fmaxf(mid.y, w3.y)), w4.y);
        float vmz = fmaxf(fmaxf(fmaxf(w0.z, w1.z), fmaxf(mid.z, w3.z)), w4.z);
        float vmw = fmaxf(fmaxf(fmaxf(w0.w, w1.w), fmaxf(mid.w, w3.w)), w4.w);
        const float2 e0 = E[(i) % 12];
        const float2 e1 = E[(i + 1) % 12];
        const float2 e2 = E[(i + 2) % 12];
        const float2 e3 = E[(i + 3) % 12];
        const float2 e4 = E[(i + 4) % 12];
        float vex = fmaxf(fmaxf(fmaxf(e0.x, e1.x), fmaxf(e2.x, e3.x)), e4.x);
        float vey = fmaxf(fmaxf(fmaxf(e0.y, e1.y), fmaxf(e2.y, e3.y)), e4.y);
        float eX = evalid ? vex : NEG;   // off the load path: post-reduction
        float eY = evalid ? vey : NEG;

        // horizontal halo: left neighbor cols (z,w), right neighbor (x,y)
        float A = __shfl_up(vmz, 1);
        float B = __shfl_up(vmw, 1);
        float C = __shfl_down(vmx, 1);
        float D = __shfl_down(vmy, 1);
        if (isL) { A = eX; B = eY; }
        if (isR) { C = eX; D = eY; }

        float t12 = fmaxf(vmy, vmz);
        float m02 = fmaxf(vmx, t12);        // max cols 0..2
        float m03 = fmaxf(m02, vmw);        // max cols 0..3
        float m13 = fmaxf(t12, vmw);        // max cols 1..3
        float h0 = fmaxf(fmaxf(A, B), m02);
        float h1 = fmaxf(B, m03);
        float h2 = fmaxf(m03, C);
        float h3 = fmaxf(m13, fmaxf(C, D));

        unsigned nib = 0;
        nib |= (mid.x > 0.0f && mid.x >= h0) ? 1u : 0u;
        nib |= (mid.y > 0.0f && mid.y >= h1) ? 2u : 0u;
        nib |= (mid.z > 0.0f && mid.z >= h2) ? 4u : 0u;
        nib |= (mid.w > 0.0f && mid.w >= h3) ? 8u : 0u;

        unsigned wd = nib << shamt;
        wd |= __shfl_xor(wd, 1);
        wd |= __shfl_xor(wd, 2);
        wd |= __shfl_xor(wd, 4);
        if (writer) {
            words[wIdx] = wd;
            cnt += __popc(wd);
        }
        wIdx += IMG_W / 32;

        if (i == 15 || i == 31) {   // flush per 16 rows
            unsigned s = cnt;
            s += __shfl_xor(s, 1);
            s += __shfl_xor(s, 2);
            s += __shfl_xor(s, 4);
            s += __shfl_xor(s, 8);
            s += __shfl_xor(s, 16);
            s += __shfl_xor(s, 32);
            if (lane == 0) bsum2[(cb0 + (i >> 4)) * 8 + strip] = s;
            cnt = 0;
        }
    }
}

// ---------------------------------------------------------------------------
// K2: scan. Reduce 8 strip-sums per 16-row chunk (8192 slots -> 1024 cbs),
// exclusive scan, base[1024] = total. One 256-thread block.
// ---------------------------------------------------------------------------
__global__ __launch_bounds__(256) void nms_scan(const unsigned* __restrict__ bsum2,
                                                unsigned* __restrict__ base) {
    __shared__ unsigned wtot[4];
    const int t = threadIdx.x;
    const int lane = t & 63, wid = t >> 6;
    const uint4* p = (const uint4*)(bsum2 + t * 32);   // 4 cbs x 8 slots
    unsigned c[4];
#pragma unroll
    for (int i = 0; i < 4; ++i) {
        uint4 a = p[2 * i], bq = p[2 * i + 1];
        c[i] = a.x + a.y + a.z + a.w + bq.x + bq.y + bq.z + bq.w;
    }
    unsigned s0 = c[0], s1 = s0 + c[1], s2 = s1 + c[2], ts = s2 + c[3];
    unsigned sc = ts;
#pragma unroll
    for (int d = 1; d < 64; d <<= 1) {
        unsigned o = __shfl_up(sc, d);
        if (lane >= d) sc += o;
    }
    if (lane == 63) wtot[wid] = sc;
    __syncthreads();
    unsigned wpre = 0;
#pragma unroll
    for (int k = 0; k < 4; ++k) wpre += (k < wid) ? wtot[k] : 0u;
    unsigned excl = wpre + sc - ts;
    ((uint4*)base)[t] = make_uint4(excl, excl + s0, excl + s1, excl + s2);
    if (t == 255) base[1024] = wpre + sc;
}

// ---------------------------------------------------------------------------
// K3: ordered compaction (blocks 0..1023) + -1 tail fill (blocks 1024..)
// ---------------------------------------------------------------------------
__global__ __launch_bounds__(256) void nms_compact(const unsigned* __restrict__ words,
                                                   const unsigned* __restrict__ base,
                                                   int* __restrict__ out) {
    const int t = threadIdx.x;
    const int b = blockIdx.x;
    if (b < 1024) {
        __shared__ unsigned wq[4];
        const int lane = t & 63, wid = t >> 6;
        uint4 q = ((const uint4*)(words + b * 1024))[t];
        unsigned wv[4] = {q.x, q.y, q.z, q.w};
        unsigned tsum = __popc(wv[0]) + __popc(wv[1]) + __popc(wv[2]) + __popc(wv[3]);
        unsigned sc = tsum;
#pragma unroll
        for (int d = 1; d < 64; d <<= 1) {
            unsigned o = __shfl_up(sc, d);
            if (lane >= d) sc += o;
        }
        if (lane == 63) wq[wid] = sc;
        __syncthreads();
        unsigned wpre = 0;
#pragma unroll
        for (int k = 0; k < 4; ++k) wpre += (k < wid) ? wq[k] : 0u;
        unsigned off = base[b] + wpre + sc - tsum;

        const unsigned gword0 = (unsigned)b * 1024u + (unsigned)t * 4u;
#pragma unroll
        for (int wi = 0; wi < 4; ++wi) {
            unsigned m = wv[wi];
            unsigned pbase = (gword0 + wi) << 5;
            while (m) {
                int bit = __builtin_ctz(m);
                m &= m - 1;
                unsigned ppix = pbase + (unsigned)bit;
                int hh = (int)((ppix >> 11) & 2047u);
                int ww = (int)(ppix & 2047u);
                if (off < (unsigned)MAX_PEAKS) {
                    out[off] = hh;
                    out[MAX_PEAKS + off] = ww;
                }
                ++off;
            }
        }
    } else {
        unsigned total = base[1024];
        if (total > (unsigned)MAX_PEAKS) total = MAX_PEAKS;
        unsigned tail = (unsigned)MAX_PEAKS - total;
        unsigned fb = (unsigned)(b - 1024);
        unsigned per = (tail + NFILL - 1) / NFILL;
        unsigned s = total + fb * per;
        unsigned e = s + per;
        if (e > (unsigned)MAX_PEAKS) e = MAX_PEAKS;
        for (unsigned k = s + t; k < e; k += 256) {
            out[k] = -1;
            out[MAX_PEAKS + k] = -1;
        }
    }
}

extern "C" void kernel_launch(void* const* d_in, const int* in_sizes, int n_in,
                              void* d_out, int out_size, void* d_ws, size_t ws_size,
                              hipStream_t stream) {
    const float* scores = (const float*)d_in[0];
    int* out = (int*)d_out;
    unsigned* words = (unsigned*)d_ws;            // 1,048,576 words (4 MB)
    unsigned* bsum2 = words + NWORDS;             // 8192 per-(chunk,strip) sums
    unsigned* base = bsum2 + 8192;                // 1025 (incl. total)

    nms_mask<<<1024, 256, 0, stream>>>(scores, words, bsum2);
    nms_scan<<<1, 256, 0, stream>>>(bsum2, base);
    nms_compact<<<1024 + NFILL, 256, 0, stream>>>(words, base, out);
}